// Round 3
// baseline (640.525 us; speedup 1.0000x reference)
//
#include <hip/hip_runtime.h>
#include <hip/hip_bf16.h>

#define DIM 384
#define HEADS 8
#define CP 48
#define NB 4
#define HIMG 128
#define WIMG 128
#define HW 16384

using bf16 = __hip_bfloat16;

typedef __attribute__((ext_vector_type(8))) short bf16x8;
typedef __attribute__((ext_vector_type(4))) float f32x4;

__device__ __forceinline__ float lo_bf(unsigned u){ union{unsigned i; float f;} c; c.i = u<<16; return c.f; }
__device__ __forceinline__ float hi_bf(unsigned u){ union{unsigned i; float f;} c; c.i = u & 0xffff0000u; return c.f; }
__device__ __forceinline__ bf16 f2bf(float v){ return __float2bfloat16(v); }
__device__ __forceinline__ unsigned bfbits(float v){ union{ bf16 h; unsigned short u; } c; c.h = f2bf(v); return (unsigned)c.u; }

__device__ __forceinline__ void st(float* p, float v){ *p = v; }
__device__ __forceinline__ void st(bf16* p, float v){ *p = f2bf(v); }

// ---------------------------------------------------------------------------
// Weight fp32 -> bf16 (Wq 384x384, Wkv 768x384), one launch.
__global__ __launch_bounds__(256) void convert_w(
    const float* __restrict__ Wq, const float* __restrict__ Wkv,
    bf16* __restrict__ Wq_bf, bf16* __restrict__ Wkv_bf)
{
  int idx = (blockIdx.x*256 + threadIdx.x) * 2;
  const int NQ = DIM*DIM;           // 147456
  const int NKV = 2*DIM*DIM;        // 294912
  if (idx < NQ) {
    unsigned u = bfbits(Wq[idx]) | (bfbits(Wq[idx+1]) << 16);
    *(unsigned*)(Wq_bf + idx) = u;
  } else {
    int j = idx - NQ;
    if (j < NKV) {
      unsigned u = bfbits(Wkv[j]) | (bfbits(Wkv[j+1]) << 16);
      *(unsigned*)(Wkv_bf + j) = u;
    }
  }
}

// ---------------------------------------------------------------------------
// B-panel-resident MFMA GEMM with fused transpose staging.
// C[b][m][n] = sum_k A[b][m][k] * B[b][k][n],  K = 384 fixed, n panel = 64.
// A bf16 [M][384] row-major (read as fragments straight from global/L2).
// B TB ([384][HW] rows, batch stride bStride) staged once into LDS as
// Bs[n][k] bf16 (XOR-swizzled k-groups). B is read exactly once from HBM.
template<typename TB, typename TOut>
__global__ __launch_bounds__(256, 2) void gemm_bpanel(
    const bf16* __restrict__ A, long aStride,
    const TB* __restrict__ B, long bStride,
    TOut* __restrict__ C, long cStride, int M)
{
  const int b  = blockIdx.z;
  const int n0 = blockIdx.x * 64;
  const bf16* Ab = A + (long)b * aStride;
  const TB*   Bb = B + (long)b * bStride;
  TOut*       Cb = C + (long)b * cStride;

  __shared__ short Bs[64*384];   // 49152 B, Bs[n][k] swizzled
  __shared__ short R[128*64];    // 16384 B, raw [k][n] slab

  const int t = threadIdx.x;
  const int w = t >> 6, lane = t & 63;
  const int quad = lane >> 4, l16 = lane & 15;

  // ---- staging: 3 slabs of 128 k ----
  for (int s = 0; s < 3; ++s) {
    const int k0 = s * 128;
    if constexpr (sizeof(TB) == 4) {
#pragma unroll
      for (int ii = 0; ii < 8; ++ii) {
        int idx = ii*256 + t;          // 0..2047
        int kr = idx >> 4, c4 = idx & 15;
        float4 v = *(const float4*)((const float*)Bb + (long)(k0+kr)*HW + n0 + c4*4);
        unsigned u0 = bfbits(v.x) | (bfbits(v.y) << 16);
        unsigned u1 = bfbits(v.z) | (bfbits(v.w) << 16);
        uint2 pk; pk.x = u0; pk.y = u1;
        *(uint2*)&R[kr*64 + c4*4] = pk;
      }
    } else {
#pragma unroll
      for (int ii = 0; ii < 4; ++ii) {
        int idx = ii*256 + t;          // 0..1023
        int kr = idx >> 3, c8 = idx & 7;
        *(uint4*)&R[kr*64 + c8*8] = *(const uint4*)((const bf16*)Bb + (long)(k0+kr)*HW + n0 + c8*8);
      }
    }
    __syncthreads();
    const int n = t & 63, kc0 = t >> 6;
#pragma unroll
    for (int jj = 0; jj < 4; ++jj) {
      int kc = kc0 + jj*4;             // 0..15
      bf16x8 val;
#pragma unroll
      for (int u = 0; u < 8; ++u) val[u] = R[(kc*8 + u)*64 + n];
      int g = (s*16 + kc) ^ (n & 7);   // swizzled k-group (0..47)
      *(bf16x8*)&Bs[n*384 + g*8] = val;
    }
    __syncthreads();
  }

  // ---- compute: waves tile M in 96-row strips, full M per pass of 384 ----
  for (int mb = 0; mb < M; mb += 384) {
    const int mw = mb + w*96;
    f32x4 acc[6][4] = {};
    for (int ks = 0; ks < 12; ++ks) {
      const int kq = ks*32 + quad*8;
      bf16x8 af[6];
#pragma unroll
      for (int mt = 0; mt < 6; ++mt)
        af[mt] = *(const bf16x8*)(Ab + (long)(mw + mt*16 + l16)*384 + kq);
      bf16x8 bfr[4];
#pragma unroll
      for (int nt = 0; nt < 4; ++nt) {
        int g = (ks*4 + quad) ^ (l16 & 7);
        bfr[nt] = *(const bf16x8*)&Bs[(nt*16 + l16)*384 + g*8];
      }
#pragma unroll
      for (int mt = 0; mt < 6; ++mt)
#pragma unroll
        for (int nt = 0; nt < 4; ++nt)
          acc[mt][nt] = __builtin_amdgcn_mfma_f32_16x16x32_bf16(af[mt], bfr[nt], acc[mt][nt], 0, 0, 0);
    }
#pragma unroll
    for (int mt = 0; mt < 6; ++mt)
#pragma unroll
      for (int nt = 0; nt < 4; ++nt)
#pragma unroll
        for (int j = 0; j < 4; ++j) {
          int row = mw + mt*16 + quad*4 + j;
          int col = n0 + nt*16 + l16;
          st(Cb + (long)row*HW + col, acc[mt][nt][j]);
        }
  }
}

// ---------------------------------------------------------------------------
// Depthwise 3x3 SAME, IN-PLACE, one block per (channel, batch) 128x128 plane.
// Results round-trip through LDS so global stores are 1KB-contiguous per
// wave instruction (fixes 2x HBM write amplification seen in R2).
__global__ __launch_bounds__(256) void dwconv_inplace(
    bf16* __restrict__ qb, bf16* __restrict__ kvb,
    const float* __restrict__ Wdw, float* __restrict__ ssq)
{
  const int ch = blockIdx.x;   // 0..1151 (q:0..383, k:384..767, v:768..1151)
  const int b  = blockIdx.y;
  bf16* plane = (ch < DIM) ? qb + ((long)b*DIM + ch)*HW
                           : kvb + ((long)b*2*DIM + (ch - DIM))*HW;
  float w9[9];
#pragma unroll
  for (int i = 0; i < 9; ++i) w9[i] = Wdw[ch*9 + i];

  __shared__ __align__(16) bf16 t_[128*140];   // compute tile, stride 140
  const int t = threadIdx.x;
#pragma unroll
  for (int i = 0; i < 16; ++i) {
    int g = i*256 + t;
    int r = g >> 5, c4 = g & 31;
    *(uint2*)&t_[r*140 + c4*4] = *(const uint2*)(plane + r*128 + c4*4);
  }
  __syncthreads();

  const int r = t >> 1, half = t & 1, cbase = half*64;
  const float mtop = (r > 0)   ? 1.f : 0.f;
  const float mbot = (r < 127) ? 1.f : 0.f;
  const int rt = (r > 0)   ? r-1 : r;
  const int rb = (r < 127) ? r+1 : r;

  float a0,a1,a2,b0,b1,b2,c0,c1,c2;
#define LD3(cc, A, B, Cv) { A = __bfloat162float(t_[rt*140 + (cc)]) * mtop; \
                            B = __bfloat162float(t_[r*140 + (cc)]); \
                            Cv = __bfloat162float(t_[rb*140 + (cc)]) * mbot; }
  if (cbase == 0) { a0=b0=c0=0.f; } else LD3(cbase-1, a0, b0, c0);
  LD3(cbase,   a1, b1, c1);
  LD3(cbase+1, a2, b2, c2);

  float ss = 0.f;
  unsigned outu[32];
#pragma unroll 4
  for (int j = 0; j < 64; ++j) {
    float o = w9[0]*a0 + w9[1]*a1 + w9[2]*a2
            + w9[3]*b0 + w9[4]*b1 + w9[5]*b2
            + w9[6]*c0 + w9[7]*c1 + w9[8]*c2;
    ss += o*o;
    unsigned ob = bfbits(o);
    if (j & 1) outu[j>>1] |= (ob << 16); else outu[j>>1] = ob;
    a0=a1; a1=a2; b0=b1; b1=b2; c0=c1; c1=c2;
    int nc = cbase + j + 2;
    if (nc <= 127) { LD3(nc, a2, b2, c2) } else { a2=b2=c2=0.f; }
  }
#undef LD3

  // LDS exchange: swizzled flat layout, then coalesced 1KB/wave stores.
  __syncthreads();   // all tile reads done before overwrite
#pragma unroll
  for (int j = 0; j < 8; ++j) {
    int G = r*16 + half*8 + j;                    // 16B granule index
    *(uint4*)&t_[(G ^ (r & 7))*8] = *(uint4*)&outu[j*4];
  }
  __syncthreads();
#pragma unroll
  for (int i = 0; i < 8; ++i) {
    int o = i*256 + t;
    uint4 vv = *(uint4*)&t_[(o ^ ((o >> 4) & 7))*8];
    *(uint4*)(plane + o*8) = vv;
  }

  if (ch < 2*DIM) {
#pragma unroll
    for (int off = 32; off; off >>= 1) ss += __shfl_down(ss, off);
    __shared__ float wsum[4];
    if ((t & 63) == 0) wsum[t >> 6] = ss;
    __syncthreads();
    if (t == 0) ssq[b*2*DIM + ch] = wsum[0]+wsum[1]+wsum[2]+wsum[3];
  }
}

// ---------------------------------------------------------------------------
// S slabs: Sp[split][b][h][48][48] = sum over this split's n-range of q.k^T
__global__ __launch_bounds__(512) void s_mfma(
    const bf16* __restrict__ qd, const bf16* __restrict__ kd,
    float* __restrict__ Sp)
{
  const int split = blockIdx.x;  // 0..7
  const int h = blockIdx.y, b = blockIdx.z;
  const int t = threadIdx.x, w = t >> 6, lane = t & 63;
  const int quad = lane >> 4, l16 = lane & 15;
  const bf16* qp = qd + ((long)b*DIM + h*CP)*HW;
  const bf16* kp = kd + ((long)b*2*DIM + h*CP)*HW;   // kv_bf batch stride = 2*DIM (fixed)
  const int nbase = (split*8 + w) * 256;

  f32x4 acc[3][3] = {};
  for (int ks = 0; ks < 8; ++ks) {
    const int n = nbase + ks*32 + quad*8;
    bf16x8 aq[3], bk[3];
#pragma unroll
    for (int i = 0; i < 3; ++i) {
      aq[i] = *(const bf16x8*)(qp + (long)(i*16 + l16)*HW + n);
      bk[i] = *(const bf16x8*)(kp + (long)(i*16 + l16)*HW + n);
    }
#pragma unroll
    for (int i = 0; i < 3; ++i)
#pragma unroll
      for (int j = 0; j < 3; ++j)
        acc[i][j] = __builtin_amdgcn_mfma_f32_16x16x32_bf16(aq[i], bk[j], acc[i][j], 0, 0, 0);
  }

  __shared__ float Sred[8][CP*CP];
#pragma unroll
  for (int i = 0; i < 3; ++i)
#pragma unroll
    for (int j = 0; j < 3; ++j)
#pragma unroll
      for (int rr = 0; rr < 4; ++rr)
        Sred[w][(i*16 + quad*4 + rr)*CP + j*16 + l16] = acc[i][j][rr];
  __syncthreads();

  float* out = Sp + (long)split*(NB*HEADS*CP*CP) + ((long)(b*HEADS + h))*CP*CP;
  for (int g = t; g < CP*CP; g += 512) {
    float s = 0.f;
#pragma unroll
    for (int ww = 0; ww < 8; ++ww) s += Sred[ww][g];
    out[g] = s;
  }
}

// ---------------------------------------------------------------------------
// logit = (sum slabs) * rsqrt(ssq_q[c]) * rsqrt(ssq_k[d]) * temp[h]; softmax
// over d; writes into slab 0 (attn).
__global__ __launch_bounds__(64) void softmax_attn(
    float* __restrict__ Sp, const float* __restrict__ ssq,
    const float* __restrict__ temp)
{
  const int bhc = blockIdx.x;
  const int c = bhc % CP;
  const int h = (bhc / CP) % HEADS;
  const int b = bhc / (CP * HEADS);
  const int lane = threadIdx.x;
  const long rowoff = ((long)(b*HEADS + h))*CP*CP + c*CP;
  const float rq = rsqrtf(ssq[b*2*DIM + h*CP + c]);
  const float tmp = temp[h];
  float logit = -1e30f;
  if (lane < CP) {
    float s = 0.f;
#pragma unroll
    for (int sl = 0; sl < 8; ++sl) s += Sp[(long)sl*(NB*HEADS*CP*CP) + rowoff + lane];
    float rk = rsqrtf(ssq[b*2*DIM + DIM + h*CP + lane]);
    logit = s * rq * rk * tmp;
  }
  float m = logit;
#pragma unroll
  for (int off = 32; off; off >>= 1) m = fmaxf(m, __shfl_down(m, off));
  m = __shfl(m, 0);
  float e = (lane < CP) ? __expf(logit - m) : 0.f;
  float s = e;
#pragma unroll
  for (int off = 32; off; off >>= 1) s += __shfl_down(s, off);
  s = __shfl(s, 0);
  if (lane < CP) Sp[rowoff + lane] = e / s;
}

// ---------------------------------------------------------------------------
// W2[b, o, h*48+d] = sum_c Wproj[o, h*48+c] * attn[b,h,c,d]   (bf16 out)
__global__ __launch_bounds__(256) void w2fold(
    const float* __restrict__ attn, const float* __restrict__ Wproj,
    bf16* __restrict__ W2)
{
  const int ot = blockIdx.x;  // o-tile of 128 (3 tiles)
  const int h  = blockIdx.y;
  const int b  = blockIdx.z;
  __shared__ float at[CP][CP];
  __shared__ float wp[128][CP];
  const int t = threadIdx.x;
  const float* Ap = attn + ((long)(b*HEADS + h))*CP*CP;
#pragma unroll
  for (int i = 0; i < 9; ++i) {
    int idx = t + 256*i;
    at[idx / CP][idx % CP] = Ap[idx];
  }
#pragma unroll
  for (int i = 0; i < 24; ++i) {
    int idx = t + 256*i;
    int o = idx / CP, c = idx % CP;
    wp[o][c] = Wproj[(long)(ot*128 + o)*DIM + h*CP + c];
  }
  __syncthreads();
#pragma unroll
  for (int i = 0; i < 24; ++i) {
    int idx = t + 256*i;
    int o = idx / CP, d = idx % CP;
    float a = 0.f;
#pragma unroll
    for (int c = 0; c < CP; ++c) a += wp[o][c] * at[c][d];
    W2[((long)b*DIM + ot*128 + o)*DIM + h*CP + d] = f2bf(a);
  }
}

// ---------------------------------------------------------------------------
extern "C" void kernel_launch(void* const* d_in, const int* in_sizes, int n_in,
                              void* d_out, int out_size, void* d_ws, size_t ws_size,
                              hipStream_t stream) {
  const float* x     = (const float*)d_in[0];
  const float* y     = (const float*)d_in[1];
  const float* Wq    = (const float*)d_in[2];
  const float* Wkv   = (const float*)d_in[3];
  const float* Wdw   = (const float*)d_in[4];
  const float* Wproj = (const float*)d_in[5];
  const float* temp  = (const float*)d_in[6];
  float* out = (float*)d_out;

  char* ws = (char*)d_ws;
  bf16*  q_bf  = (bf16*)(ws + 0L);               // 4*384*16384*2  = 50331648
  bf16*  kv_bf = (bf16*)(ws + 50331648L);        // 4*768*16384*2  = 100663296
  char* tail   = ws + 150994944L;
  bf16* Wq_bf  = (bf16*)(tail);                  // 294912  (dead before Sp)
  bf16* Wkv_bf = (bf16*)(tail + 294912L);        // 589824  (dead before Sp)
  float* Sp    = (float*)(tail);                 // 8 slabs x 294912 = 2359296; slab0 -> attn
  bf16* W2_bf  = (bf16*)(tail + 294912L);        // 1179648 (over dead slabs 1-4)
  float* ssq   = (float*)(tail + 2359296L);      // 12288
  bf16* vd     = kv_bf + (long)DIM*HW;           // v slice (batch stride 2*DIM*HW)

  // 1. weights -> bf16
  convert_w<<<864, 256, 0, stream>>>(Wq, Wkv, Wq_bf, Wkv_bf);
  // 2. q = Wq @ x  (reads x fp32 once, fused transpose staging)
  gemm_bpanel<float, bf16><<<dim3(HW/64, 1, NB), 256, 0, stream>>>(
      Wq_bf, 0, x, (long)DIM*HW, q_bf, (long)DIM*HW, DIM);
  // 3. kv = Wkv @ y
  gemm_bpanel<float, bf16><<<dim3(HW/64, 1, NB), 256, 0, stream>>>(
      Wkv_bf, 0, y, (long)DIM*HW, kv_bf, (long)2*DIM*HW, 2*DIM);
  // 4. depthwise 3x3 in-place + ssq
  dwconv_inplace<<<dim3(3*DIM, NB), 256, 0, stream>>>(q_bf, kv_bf, Wdw, ssq);
  // 5. raw scores (8 slabs)
  s_mfma<<<dim3(8, HEADS, NB), 512, 0, stream>>>(q_bf, kv_bf, Sp);
  // 6. softmax with folded l2norm + temperature (into slab 0)
  softmax_attn<<<dim3(NB*HEADS*CP), 64, 0, stream>>>(Sp, ssq, temp);
  // 7. fold Wproj through attn -> bf16
  w2fold<<<dim3(3, HEADS, NB), 256, 0, stream>>>(Sp, Wproj, W2_bf);
  // 8. out = W2 @ vd
  gemm_bpanel<bf16, float><<<dim3(HW/64, 1, NB), 256, 0, stream>>>(
      W2_bf, (long)DIM*DIM, vd, (long)2*DIM*HW, out, (long)DIM*HW, DIM);
}